// Round 13
// baseline (1224.949 us; speedup 1.0000x reference)
//
#include <hip/hip_runtime.h>
#include <hip/hip_bf16.h>
#include <math.h>

// ---------------------------------------------------------------------------
// MEASUREMENT ROUND: r7 champion structure, each kernel body repeated
// REP times (idempotent; memory-clobber per rep prevents hoisting) so every
// kernel rises above the harness's ~41us fill dispatches and shows up in the
// top-5 rocprof rows with counters. True per-kernel time = dur / REP.
// base_acc reps>0 accumulate into dead scratch (c2o, already consumed).
// ---------------------------------------------------------------------------

#define CONV_FLAT 32768
#define H1_  304
#define H2_  176
#define OUT_ 48
#define CPB  4

#define REP_C1   12
#define REP_C2   10
#define REP_C3   16
#define REP_BA   8
#define REP_CK   2

// ws layout (float offsets)
#define WS_C1    0          // 8*128*128  = 131072
#define WS_C2    131072     // 16*64*64   = 65536
#define WS_XC    196608     // 32*32*32   = 32768
#define WS_BASE  229376     // 320
#define WS_W1PCT 229696     // 18*304     = 5472
#define WS_W2Q   235168     // 76*176*4   = 53504  (w2 packed [k/4][t][4])
#define WS_W3Q   288672     // 44*48*4    = 8448   (w3 packed [k/4][t][4])

__global__ void conv1_prep_k(const float* __restrict__ x, const float* __restrict__ cw,
                             const float* __restrict__ cb, const float* __restrict__ w1,
                             const float* __restrict__ w2, const float* __restrict__ w3,
                             const float* __restrict__ b1, float* __restrict__ out,
                             float* __restrict__ w1pcT, float* __restrict__ w2q,
                             float* __restrict__ w3q, float* __restrict__ base) {
    for (int rep = 0; rep < REP_C1; rep++) {
        if (blockIdx.x >= 2048) {   // prep tail
            int idx = (blockIdx.x - 2048) * 256 + threadIdx.x;
            if (idx < 304 * 176) {
                int t = idx / 304, k = idx - t * 304;
                w2q[(k >> 2) * (H2_ * 4) + t * 4 + (k & 3)] = w2[idx];
            }
            if (idx < 48 * 176) {
                int t = idx / 176, k = idx - t * 176;
                w3q[(k >> 2) * 192 + t * 4 + (k & 3)] = w3[idx];
            }
            if (idx < 304 * 18) {
                int t = idx / 18, k = idx - t * 18;
                w1pcT[k * 304 + t] = w1[(size_t)t * 32786 + 32768 + k];
            }
            if (idx < H1_) base[idx] = b1[idx];
        } else {
            int idx = blockIdx.x * 256 + threadIdx.x;
            int sub = idx & 3;
            int p   = idx >> 2;
            int o  = p >> 14;
            int py = (p >> 7) & 127, px = p & 127;
            int y = py * 2 + (sub >> 1), xx = px * 2 + (sub & 1);
            const float* wo = cw + o * 9;
            float acc = cb[o];
            if (y > 0 && y < 255 && xx > 0 && xx < 255) {
                const float* r = x + (y - 1) * 256 + (xx - 1);
                acc += r[0]*wo[0] + r[1]*wo[1] + r[2]*wo[2]
                     + r[256]*wo[3] + r[257]*wo[4] + r[258]*wo[5]
                     + r[512]*wo[6] + r[513]*wo[7] + r[514]*wo[8];
            } else {
#pragma unroll
                for (int ky = 0; ky < 3; ky++) {
                    int sy = y + ky - 1;
                    if ((unsigned)sy > 255u) continue;
                    const float* row = x + sy * 256;
#pragma unroll
                    for (int kx = 0; kx < 3; kx++) {
                        int sx = xx + kx - 1;
                        if ((unsigned)sx > 255u) continue;
                        acc += row[sx] * wo[ky * 3 + kx];
                    }
                }
            }
            acc = fmaxf(acc, __shfl_xor(acc, 1, 64));
            acc = fmaxf(acc, __shfl_xor(acc, 2, 64));
            if (sub == 0) out[p] = fmaxf(acc, 0.f);
        }
        asm volatile("" ::: "memory");
    }
}

__global__ void conv2_k(const float* __restrict__ in, const float* __restrict__ w,
                        const float* __restrict__ b, float* __restrict__ out) {
    for (int rep = 0; rep < REP_C2; rep++) {
        int idx = blockIdx.x * blockDim.x + threadIdx.x;
        int sub = idx & 3;
        int p   = idx >> 2;
        int o  = p >> 12;
        int py = (p >> 6) & 63, px = p & 63;
        int y = py * 2 + (sub >> 1), xx = px * 2 + (sub & 1);
        float acc = b[o];
        const float* wo = w + o * 72;
        if (y > 0 && y < 127 && xx > 0 && xx < 127) {
            const float* bi = in + (y - 1) * 128 + (xx - 1);
#pragma unroll
            for (int c = 0; c < 8; c++) {
                const float* r  = bi + c * 16384;
                const float* wc = wo + c * 9;
                acc += r[0]*wc[0] + r[1]*wc[1] + r[2]*wc[2]
                     + r[128]*wc[3] + r[129]*wc[4] + r[130]*wc[5]
                     + r[256]*wc[6] + r[257]*wc[7] + r[258]*wc[8];
            }
        } else {
#pragma unroll
            for (int c = 0; c < 8; c++) {
                const float* inc = in + c * 16384;
                const float* wc  = wo + c * 9;
#pragma unroll
                for (int ky = 0; ky < 3; ky++) {
                    int sy = y + ky - 1;
                    if ((unsigned)sy > 127u) continue;
                    const float* row = inc + sy * 128;
#pragma unroll
                    for (int kx = 0; kx < 3; kx++) {
                        int sx = xx + kx - 1;
                        if ((unsigned)sx > 127u) continue;
                        acc += row[sx] * wc[ky * 3 + kx];
                    }
                }
            }
        }
        acc = fmaxf(acc, __shfl_xor(acc, 1, 64));
        acc = fmaxf(acc, __shfl_xor(acc, 2, 64));
        if (sub == 0) out[p] = fmaxf(acc, 0.f);
        asm volatile("" ::: "memory");
    }
}

__global__ void conv3_k(const float* __restrict__ in, const float* __restrict__ w,
                        const float* __restrict__ b, float* __restrict__ out) {
    for (int rep = 0; rep < REP_C3; rep++) {
        int idx = blockIdx.x * blockDim.x + threadIdx.x;
        int sub = idx & 3;
        int p   = idx >> 2;
        int o  = p >> 10;
        int py = (p >> 5) & 31, px = p & 31;
        int y = py * 2 + (sub >> 1), xx = px * 2 + (sub & 1);
        float acc = b[o];
        const float* wo = w + o * 144;
        if (y > 0 && y < 63 && xx > 0 && xx < 63) {
            const float* bi = in + (y - 1) * 64 + (xx - 1);
#pragma unroll
            for (int c = 0; c < 16; c++) {
                const float* r  = bi + c * 4096;
                const float* wc = wo + c * 9;
                acc += r[0]*wc[0] + r[1]*wc[1] + r[2]*wc[2]
                     + r[64]*wc[3] + r[65]*wc[4] + r[66]*wc[5]
                     + r[128]*wc[6] + r[129]*wc[7] + r[130]*wc[8];
            }
        } else {
#pragma unroll
            for (int c = 0; c < 16; c++) {
                const float* inc = in + c * 4096;
                const float* wc  = wo + c * 9;
#pragma unroll
                for (int ky = 0; ky < 3; ky++) {
                    int sy = y + ky - 1;
                    if ((unsigned)sy > 63u) continue;
                    const float* row = inc + sy * 64;
#pragma unroll
                    for (int kx = 0; kx < 3; kx++) {
                        int sx = xx + kx - 1;
                        if ((unsigned)sx > 63u) continue;
                        acc += row[sx] * wc[ky * 3 + kx];
                    }
                }
            }
        }
        acc = fmaxf(acc, __shfl_xor(acc, 1, 64));
        acc = fmaxf(acc, __shfl_xor(acc, 2, 64));
        if (sub == 0) out[p] = fmaxf(acc, 0.f);
        asm volatile("" ::: "memory");
    }
}

// split-K: base[row] += dot(w1[row, seg], xconv[seg]); base pre-init to b1
// reps > 0 accumulate into dead scratch (c2o — already consumed by conv3)
#define NSEG 16
#define SEGLEN (CONV_FLAT / NSEG)   // 2048 floats
__global__ void base_acc_k(const float* __restrict__ w1, const float* __restrict__ xconv,
                           float* __restrict__ base, float* __restrict__ base_dead) {
    for (int rep = 0; rep < REP_BA; rep++) {
        float* tgt = (rep == 0) ? base : base_dead;
        int row = blockIdx.x >> 4;
        int seg = blockIdx.x & 15;
        const float2* wr = (const float2*)(w1 + (size_t)row * 32786) + seg * (SEGLEN / 2);
        const float2* xc = (const float2*)(xconv) + seg * (SEGLEN / 2);
        float acc = 0.f;
#pragma unroll
        for (int i = 0; i < 4; i++) {
            float2 a = wr[threadIdx.x + i * 256];
            float2 v = xc[threadIdx.x + i * 256];
            acc += a.x * v.x + a.y * v.y;
        }
#pragma unroll
        for (int off = 32; off > 0; off >>= 1)
            acc += __shfl_down(acc, off, 64);
        __shared__ float red[4];
        int lane = threadIdx.x & 63, wid = threadIdx.x >> 6;
        if (lane == 0) red[wid] = acc;
        __syncthreads();
        if (threadIdx.x == 0)
            atomicAdd(&tgt[row], red[0] + red[1] + red[2] + red[3]);
        __syncthreads();
        asm volatile("" ::: "memory");
    }
}

// fused per-chunk MLP, 4 chunks per block, 1024 blocks
__global__ void chunk_k(const float* __restrict__ x, const float* __restrict__ base,
                        const float* __restrict__ w1pcT, const float* __restrict__ w2q,
                        const float* __restrict__ b2, const float* __restrict__ w3q,
                        const float* __restrict__ b3, float* __restrict__ out) {
    __shared__ float pc[CPB][18];
    __shared__ float h1[CPB][H1_];
    __shared__ float h2s[CPB][H2_];
    int tid = threadIdx.x;
    int c0 = blockIdx.x * CPB;

    for (int rep = 0; rep < REP_CK; rep++) {
        __syncthreads();
        if (tid < CPB * 18) {
            int u = tid / 18, k = tid - u * 18;
            int c = c0 + u;
            int i = c >> 6, j = c & 63;
            float v;
            if (k == 0)      v = (float)(i * 4);
            else if (k == 1) v = (float)(j * 4);
            else {
                int kk = k - 2;
                int r = kk >> 2, cc = kk & 3;
                v = x[(i * 4 + r) * 256 + j * 4 + cc];
            }
            pc[u][k] = v;
        }
        __syncthreads();

        for (int t = tid; t < H1_; t += 256) {
            float bb = base[t];
            float acc[CPB];
#pragma unroll
            for (int u = 0; u < CPB; u++) acc[u] = bb;
#pragma unroll
            for (int k = 0; k < 18; k++) {
                float w = w1pcT[k * H1_ + t];
#pragma unroll
                for (int u = 0; u < CPB; u++) acc[u] += w * pc[u][k];
            }
#pragma unroll
            for (int u = 0; u < CPB; u++) h1[u][t] = fmaxf(acc[u], 0.f);
        }
        __syncthreads();

        if (tid < H2_) {
            const float4* wq = (const float4*)w2q;
            float acc[CPB];
#pragma unroll
            for (int u = 0; u < CPB; u++) acc[u] = b2[tid];
#pragma unroll 4
            for (int g = 0; g < 76; g++) {
                float4 w = wq[g * H2_ + tid];
#pragma unroll
                for (int u = 0; u < CPB; u++) {
                    float4 h = *(const float4*)&h1[u][g * 4];
                    acc[u] += w.x * h.x + w.y * h.y + w.z * h.z + w.w * h.w;
                }
            }
#pragma unroll
            for (int u = 0; u < CPB; u++) h2s[u][tid] = fmaxf(acc[u], 0.f);
        }
        __syncthreads();

        if (tid < CPB * OUT_) {
            int u = tid / OUT_, t = tid - u * OUT_;
            const float4* wq = (const float4*)w3q;
            float acc = b3[t];
#pragma unroll 4
            for (int g = 0; g < 44; g++) {
                float4 w = wq[g * OUT_ + t];
                float4 h = *(const float4*)&h2s[u][g * 4];
                acc += w.x * h.x + w.y * h.y + w.z * h.z + w.w * h.w;
            }
            out[(size_t)(c0 + u) * OUT_ + t] = 1.f / (1.f + expf(-acc));
        }
        asm volatile("" ::: "memory");
    }
}

extern "C" void kernel_launch(void* const* d_in, const int* in_sizes, int n_in,
                              void* d_out, int out_size, void* d_ws, size_t ws_size,
                              hipStream_t stream) {
    const float* x    = (const float*)d_in[0];
    const float* c1_w = (const float*)d_in[1];
    const float* c1_b = (const float*)d_in[2];
    const float* c2_w = (const float*)d_in[3];
    const float* c2_b = (const float*)d_in[4];
    const float* c3_w = (const float*)d_in[5];
    const float* c3_b = (const float*)d_in[6];
    const float* w1   = (const float*)d_in[7];
    const float* b1   = (const float*)d_in[8];
    const float* w2   = (const float*)d_in[9];
    const float* b2   = (const float*)d_in[10];
    const float* w3   = (const float*)d_in[11];
    const float* b3   = (const float*)d_in[12];
    float* out = (float*)d_out;
    float* ws  = (float*)d_ws;

    float* c1o    = ws + WS_C1;
    float* c2o    = ws + WS_C2;
    float* xconv  = ws + WS_XC;
    float* base   = ws + WS_BASE;
    float* w1pcT  = ws + WS_W1PCT;
    float* w2q    = ws + WS_W2Q;
    float* w3q    = ws + WS_W3Q;

    conv1_prep_k<<<2048 + 209, 256, 0, stream>>>(x, c1_w, c1_b, w1, w2, w3, b1,
                                                 c1o, w1pcT, w2q, w3q, base);
    conv2_k<<<1024, 256, 0, stream>>>(c1o, c2_w, c2_b, c2o);
    conv3_k<<<512, 256, 0, stream>>>(c2o, c3_w, c3_b, xconv);
    base_acc_k<<<H1_ * NSEG, 256, 0, stream>>>(w1, xconv, base, c2o /*dead*/);
    chunk_k<<<1024, 256, 0, stream>>>(x, base, w1pcT, w2q, b2, w3q, b3, out);
}

// Round 14
// 53.302 us; speedup vs baseline: 22.9811x; 22.9811x over previous
//
#include <hip/hip_runtime.h>
#include <hip/hip_bf16.h>
#include <math.h>

// ---------------------------------------------------------------------------
// ColorizationNet inference, 3 kernels:
//  1) fused_conv_prep_k: conv1+pool+conv2+pool+conv3+pool fully fused per
//     2x2-output tile (256 blocks, LDS-staged recompute; r13 measurement
//     showed conv3 alone = 56us/inv, FETCH 26.5MB for a 256KB input —
//     cross-kernel ws staging misses L2; fusion removes the ws round-trips).
//     Prep (w2q/w3q/w1pcT/base=b1) rides in 209 tail blocks.
//  2) base_acc_k: base[304] += w1[:, :32768] @ xconv (split-K 16, atomics)
//  3) chunk_k: per-chunk MLP, CPB=4 @1024 blocks (proven optimum r3/r7)
// ---------------------------------------------------------------------------

#define CONV_FLAT 32768
#define H1_  304
#define H2_  176
#define OUT_ 48
#define CPB  4

// ws layout (float offsets)
#define WS_XC    196608     // 32*32*32   = 32768 (xconv)
#define WS_BASE  229376     // 320
#define WS_W1PCT 229696     // 18*304     = 5472
#define WS_W2Q   235168     // 76*176*4   = 53504  (w2 packed [k/4][t][4])
#define WS_W3Q   288672     // 44*48*4    = 8448   (w3 packed [k/4][t][4])

// ---------------- fused conv backbone (+ weight prep tail) ------------------
// tile: xconv[:, 2ti:2ti+2, 2tj:2tj+2]; 16x16 tiles = 256 blocks
__global__ __launch_bounds__(256)
void fused_conv_prep_k(const float* __restrict__ x,
                       const float* __restrict__ c1w, const float* __restrict__ c1b,
                       const float* __restrict__ c2w, const float* __restrict__ c2b,
                       const float* __restrict__ c3w, const float* __restrict__ c3b,
                       const float* __restrict__ w1, const float* __restrict__ w2,
                       const float* __restrict__ w3, const float* __restrict__ b1,
                       float* __restrict__ xconv, float* __restrict__ w1pcT,
                       float* __restrict__ w2q, float* __restrict__ w3q,
                       float* __restrict__ base) {
    int tid = threadIdx.x;
    if (blockIdx.x >= 256) {        // ---- prep tail (209 blocks) ----
        int idx = (blockIdx.x - 256) * 256 + tid;
        if (idx < 304 * 176) {                     // w2 row-major [176][304]
            int t = idx / 304, k = idx - t * 304;
            w2q[(k >> 2) * (H2_ * 4) + t * 4 + (k & 3)] = w2[idx];
        }
        if (idx < 48 * 176) {                      // w3 row-major [48][176]
            int t = idx / 176, k = idx - t * 176;
            w3q[(k >> 2) * 192 + t * 4 + (k & 3)] = w3[idx];
        }
        if (idx < 304 * 18) {                      // w1[:, 32768+k]
            int t = idx / 18, k = idx - t * 18;
            w1pcT[k * 304 + t] = w1[(size_t)t * 32786 + 32768 + k];
        }
        if (idx < H1_) base[idx] = b1[idx];
        return;
    }
    int ti = blockIdx.x >> 4, tj = blockIdx.x & 15;

    __shared__ float xl[30][30];        // x halo:  rows 16ti-7 .. 16ti+22
    __shared__ float c1l[8][14][14];    // c1 pooled rows 8ti-3 .. 8ti+10
    __shared__ float c2l[16][6][6];     // c2 pooled rows 4ti-1 .. 4ti+4

    // ---- stage x halo ----
    for (int e = tid; e < 900; e += 256) {
        int a = e / 30, b = e - a * 30;
        int gy = 16 * ti - 7 + a, gx = 16 * tj - 7 + b;
        float v = 0.f;
        if ((unsigned)gy < 256u && (unsigned)gx < 256u) v = x[gy * 256 + gx];
        xl[a][b] = v;
    }
    __syncthreads();

    // ---- conv1 + relu + pool -> c1l (8 x 14 x 14 = 1568) ----
    for (int e = tid; e < 1568; e += 256) {
        int c = e / 196, r = e - c * 196;
        int a = r / 14, b = r - a * 14;
        int gv = 8 * ti - 3 + a, gu = 8 * tj - 3 + b;   // pooled coords
        float val = 0.f;
        if ((unsigned)gv < 128u && (unsigned)gu < 128u) {
            const float* wp = c1w + c * 9;
            float bias = c1b[c];
            float s00 = bias, s01 = bias, s10 = bias, s11 = bias;
#pragma unroll
            for (int ky = 0; ky < 3; ky++) {
#pragma unroll
                for (int kx = 0; kx < 3; kx++) {
                    float wv = wp[ky * 3 + kx];
                    s00 += xl[2 * a + 0 + ky][2 * b + 0 + kx] * wv;
                    s01 += xl[2 * a + 0 + ky][2 * b + 1 + kx] * wv;
                    s10 += xl[2 * a + 1 + ky][2 * b + 0 + kx] * wv;
                    s11 += xl[2 * a + 1 + ky][2 * b + 1 + kx] * wv;
                }
            }
            val = fmaxf(fmaxf(fmaxf(s00, s01), fmaxf(s10, s11)), 0.f);
        }
        c1l[c][a][b] = val;
    }
    __syncthreads();

    // ---- conv2 + relu + pool -> c2l (16 x 6 x 6 = 576) ----
    for (int e = tid; e < 576; e += 256) {
        int c = e / 36, r = e - c * 36;
        int a = r / 6, b = r - a * 6;
        int gsy = 4 * ti - 1 + a, gsx = 4 * tj - 1 + b;   // pooled coords
        float val = 0.f;
        if ((unsigned)gsy < 64u && (unsigned)gsx < 64u) {
            float bias = c2b[c];
            float s00 = bias, s01 = bias, s10 = bias, s11 = bias;
            const float* wb = c2w + c * 72;
#pragma unroll
            for (int ic = 0; ic < 8; ic++) {
                const float* wp = wb + ic * 9;
#pragma unroll
                for (int ky = 0; ky < 3; ky++) {
#pragma unroll
                    for (int kx = 0; kx < 3; kx++) {
                        float wv = wp[ky * 3 + kx];
                        s00 += c1l[ic][2 * a + 0 + ky][2 * b + 0 + kx] * wv;
                        s01 += c1l[ic][2 * a + 0 + ky][2 * b + 1 + kx] * wv;
                        s10 += c1l[ic][2 * a + 1 + ky][2 * b + 0 + kx] * wv;
                        s11 += c1l[ic][2 * a + 1 + ky][2 * b + 1 + kx] * wv;
                    }
                }
            }
            val = fmaxf(fmaxf(fmaxf(s00, s01), fmaxf(s10, s11)), 0.f);
        }
        c2l[c][a][b] = val;
    }
    __syncthreads();

    // ---- conv3 + relu + pool -> xconv (32 och x 2 x 2 = 128) ----
    if (tid < 128) {
        int oc = tid >> 2, ql = tid & 3;
        int qly = ql >> 1, qlx = ql & 1;
        float bias = c3b[oc];
        float s00 = bias, s01 = bias, s10 = bias, s11 = bias;
        const float* wb = c3w + oc * 144;
#pragma unroll
        for (int ic = 0; ic < 16; ic++) {
            const float* wp = wb + ic * 9;
#pragma unroll
            for (int ky = 0; ky < 3; ky++) {
#pragma unroll
                for (int kx = 0; kx < 3; kx++) {
                    float wv = wp[ky * 3 + kx];
                    s00 += c2l[ic][2 * qly + 0 + ky][2 * qlx + 0 + kx] * wv;
                    s01 += c2l[ic][2 * qly + 0 + ky][2 * qlx + 1 + kx] * wv;
                    s10 += c2l[ic][2 * qly + 1 + ky][2 * qlx + 0 + kx] * wv;
                    s11 += c2l[ic][2 * qly + 1 + ky][2 * qlx + 1 + kx] * wv;
                }
            }
        }
        float val = fmaxf(fmaxf(fmaxf(s00, s01), fmaxf(s10, s11)), 0.f);
        xconv[oc * 1024 + (2 * ti + qly) * 32 + (2 * tj + qlx)] = val;
    }
}

// split-K: base[row] += dot(w1[row, seg], xconv[seg]); base pre-init to b1
#define NSEG 16
#define SEGLEN (CONV_FLAT / NSEG)   // 2048 floats
__global__ void base_acc_k(const float* __restrict__ w1, const float* __restrict__ xconv,
                           float* __restrict__ base) {
    int row = blockIdx.x >> 4;
    int seg = blockIdx.x & 15;
    const float2* wr = (const float2*)(w1 + (size_t)row * 32786) + seg * (SEGLEN / 2);
    const float2* xc = (const float2*)(xconv) + seg * (SEGLEN / 2);
    float acc = 0.f;
#pragma unroll
    for (int i = 0; i < 4; i++) {
        float2 a = wr[threadIdx.x + i * 256];
        float2 v = xc[threadIdx.x + i * 256];
        acc += a.x * v.x + a.y * v.y;
    }
#pragma unroll
    for (int off = 32; off > 0; off >>= 1)
        acc += __shfl_down(acc, off, 64);
    __shared__ float red[4];
    int lane = threadIdx.x & 63, wid = threadIdx.x >> 6;
    if (lane == 0) red[wid] = acc;
    __syncthreads();
    if (threadIdx.x == 0)
        atomicAdd(&base[row], red[0] + red[1] + red[2] + red[3]);
}

// fused per-chunk MLP, 4 chunks per block, 1024 blocks (proven optimum)
__global__ void chunk_k(const float* __restrict__ x, const float* __restrict__ base,
                        const float* __restrict__ w1pcT, const float* __restrict__ w2q,
                        const float* __restrict__ b2, const float* __restrict__ w3q,
                        const float* __restrict__ b3, float* __restrict__ out) {
    __shared__ float pc[CPB][18];
    __shared__ float h1[CPB][H1_];
    __shared__ float h2s[CPB][H2_];
    int tid = threadIdx.x;
    int c0 = blockIdx.x * CPB;

    if (tid < CPB * 18) {
        int u = tid / 18, k = tid - u * 18;
        int c = c0 + u;
        int i = c >> 6, j = c & 63;
        float v;
        if (k == 0)      v = (float)(i * 4);
        else if (k == 1) v = (float)(j * 4);
        else {
            int kk = k - 2;
            int r = kk >> 2, cc = kk & 3;
            v = x[(i * 4 + r) * 256 + j * 4 + cc];
        }
        pc[u][k] = v;
    }
    __syncthreads();

    // h1: 304 outputs x 4 chunks
    for (int t = tid; t < H1_; t += 256) {
        float bb = base[t];
        float acc[CPB];
#pragma unroll
        for (int u = 0; u < CPB; u++) acc[u] = bb;
#pragma unroll
        for (int k = 0; k < 18; k++) {
            float w = w1pcT[k * H1_ + t];
#pragma unroll
            for (int u = 0; u < CPB; u++) acc[u] += w * pc[u][k];
        }
#pragma unroll
        for (int u = 0; u < CPB; u++) h1[u][t] = fmaxf(acc[u], 0.f);
    }
    __syncthreads();

    // h2: 176 outputs x 4 chunks
    if (tid < H2_) {
        const float4* wq = (const float4*)w2q;   // [76][176] float4s
        float acc[CPB];
#pragma unroll
        for (int u = 0; u < CPB; u++) acc[u] = b2[tid];
#pragma unroll 4
        for (int g = 0; g < 76; g++) {
            float4 w = wq[g * H2_ + tid];
#pragma unroll
            for (int u = 0; u < CPB; u++) {
                float4 h = *(const float4*)&h1[u][g * 4];
                acc[u] += w.x * h.x + w.y * h.y + w.z * h.z + w.w * h.w;
            }
        }
#pragma unroll
        for (int u = 0; u < CPB; u++) h2s[u][tid] = fmaxf(acc[u], 0.f);
    }
    __syncthreads();

    // out: 48 outputs x 4 chunks = 192 threads
    if (tid < CPB * OUT_) {
        int u = tid / OUT_, t = tid - u * OUT_;
        const float4* wq = (const float4*)w3q;   // [44][48] float4s
        float acc = b3[t];
#pragma unroll 4
        for (int g = 0; g < 44; g++) {
            float4 w = wq[g * OUT_ + t];
            float4 h = *(const float4*)&h2s[u][g * 4];
            acc += w.x * h.x + w.y * h.y + w.z * h.z + w.w * h.w;
        }
        out[(size_t)(c0 + u) * OUT_ + t] = 1.f / (1.f + expf(-acc));
    }
}

extern "C" void kernel_launch(void* const* d_in, const int* in_sizes, int n_in,
                              void* d_out, int out_size, void* d_ws, size_t ws_size,
                              hipStream_t stream) {
    const float* x    = (const float*)d_in[0];
    const float* c1_w = (const float*)d_in[1];
    const float* c1_b = (const float*)d_in[2];
    const float* c2_w = (const float*)d_in[3];
    const float* c2_b = (const float*)d_in[4];
    const float* c3_w = (const float*)d_in[5];
    const float* c3_b = (const float*)d_in[6];
    const float* w1   = (const float*)d_in[7];
    const float* b1   = (const float*)d_in[8];
    const float* w2   = (const float*)d_in[9];
    const float* b2   = (const float*)d_in[10];
    const float* w3   = (const float*)d_in[11];
    const float* b3   = (const float*)d_in[12];
    float* out = (float*)d_out;
    float* ws  = (float*)d_ws;

    float* xconv  = ws + WS_XC;
    float* base   = ws + WS_BASE;
    float* w1pcT  = ws + WS_W1PCT;
    float* w2q    = ws + WS_W2Q;
    float* w3q    = ws + WS_W3Q;

    fused_conv_prep_k<<<256 + 209, 256, 0, stream>>>(
        x, c1_w, c1_b, c2_w, c2_b, c3_w, c3_b, w1, w2, w3, b1,
        xconv, w1pcT, w2q, w3q, base);
    base_acc_k<<<H1_ * NSEG, 256, 0, stream>>>(w1, xconv, base);
    chunk_k<<<1024, 256, 0, stream>>>(x, base, w1pcT, w2q, b2, w3q, b3, out);
}